// Round 3
// baseline (409.094 us; speedup 1.0000x reference)
//
#include <hip/hip_runtime.h>
#include <stdint.h>

#define BATCH 2
#define SEQ   2048
#define DM    1024
#define NH    16
#define DK    64

#define MEG4 4194304UL
#define MEG1 1048576UL
// ws layout (bf16 element offsets):
//   [0, 4M)    q_ws   (Q proj, [B,H,S,dk])
//   [4M, 8M)   k_ws   (K proj, [B,H,S,dk])
//   [8M, 12M)  vt_ws  (V proj transposed, [B,H,dk,S])
//   [12M,16M)  o_ws   (attn out, [B,S,D])
//   [16M,20M)  staged q ; [20M,24M) k ; [24M,28M) v
//   [28M,29M)  wq ; [29M,30M) wk ; [30M,31M) wv ; [31M,32M) wo
//   [32M + 1024*{0,1,2,3})  bq,bk,bv,bo
//   flag (uint32) at elem offset 32M+8192
#define STAGE_BASE (4 * MEG4)
#define SB         (8 * MEG4)
#define FLAG_OFF   (SB + 8192)

typedef __bf16 v8bf __attribute__((ext_vector_type(8)));
typedef float  v4f  __attribute__((ext_vector_type(4)));

static __device__ __forceinline__ float bf2f(uint16_t u) {
    union { uint32_t i; float f; } c; c.i = ((uint32_t)u) << 16; return c.f;
}
static __device__ __forceinline__ uint16_t f2bf(float f) {
    union { float f; uint32_t i; } c; c.f = f;
    uint32_t x = c.i;
    return (uint16_t)((x + 0x7fffu + ((x >> 16) & 1u)) >> 16);
}

// ---------------------------------------------------------------------------
// Dtype detection: scan first 1M uint16 words of q for bf16 NaN/Inf patterns.
// Finite bf16 data -> 0 hits. fp32 data reinterpreted -> ~2000 hits (random
// low mantissa halves hit exp=0xFF at rate 2^-8). flag=1 means fp32 inputs.
// ---------------------------------------------------------------------------
__global__ __launch_bounds__(1024) void detect_kernel(
    const uint16_t* __restrict__ q, uint32_t* __restrict__ flag)
{
    __shared__ uint32_t cnt;
    if (threadIdx.x == 0) cnt = 0;
    __syncthreads();
    uint32_t local = 0;
    for (int i = threadIdx.x; i < (1 << 20); i += 1024) {
        uint16_t w = q[i];
        if ((w & 0x7F80u) == 0x7F80u) local++;
    }
    atomicAdd(&cnt, local);
    __syncthreads();
    if (threadIdx.x == 0) *flag = (cnt >= 64u) ? 1u : 0u;
}

// ---------------------------------------------------------------------------
// Stage all 11 float tensors into ws as bf16 (copy if already bf16).
// ---------------------------------------------------------------------------
__global__ __launch_bounds__(256) void convert_kernel(
    const void* s0, const void* s1, const void* s2, const void* s3,
    const void* s4, const void* s5, const void* s6, const void* s7,
    const void* s8, const void* s9, const void* s10,
    uint16_t* __restrict__ ws, const uint32_t* __restrict__ flag)
{
    // z order: q,k,v, wq,bq, wk,bk, wv,bv, wo,bo
    constexpr size_t SZ[11]  = {MEG4, MEG4, MEG4, MEG1, 1024, MEG1, 1024,
                                MEG1, 1024, MEG1, 1024};
    constexpr size_t OFF[11] = {STAGE_BASE, STAGE_BASE + MEG4, STAGE_BASE + 2 * MEG4,
                                7 * MEG4,          SB + 0,
                                7 * MEG4 + MEG1,   SB + 1024,
                                7 * MEG4 + 2*MEG1, SB + 2048,
                                7 * MEG4 + 3*MEG1, SB + 3072};
    const int z = blockIdx.y;
    size_t i0 = ((size_t)blockIdx.x * 256 + threadIdx.x) * 8;
    if (i0 >= SZ[z]) return;
    const void* src;
    switch (z) {
        case 0: src = s0; break;  case 1: src = s1; break;
        case 2: src = s2; break;  case 3: src = s3; break;
        case 4: src = s4; break;  case 5: src = s5; break;
        case 6: src = s6; break;  case 7: src = s7; break;
        case 8: src = s8; break;  case 9: src = s9; break;
        default: src = s10; break;
    }
    uint16_t* dst = ws + OFF[z] + i0;
    if (*flag) {
        const float* s = (const float*)src + i0;
#pragma unroll
        for (int t = 0; t < 8; t++) dst[t] = f2bf(s[t]);
    } else {
        const uint16_t* s = (const uint16_t*)src + i0;
#pragma unroll
        for (int t = 0; t < 8; t++) dst[t] = s[t];
    }
}

// ---------------------------------------------------------------------------
// gemm_bt core: C[M,N] = A[M,K] @ W[N,K]^T + bias[N], M=4096, N=K=1024.
// 128x128 block tile, BK=32, 4 waves 2x2, 16x16x32 bf16 MFMA.
// mode: 0 -> [B,H,S,dk]; 2 -> [B,H,dk,S]; 3 -> row-major [M,N] (dtype per f32out).
// ---------------------------------------------------------------------------
__device__ __forceinline__ void gemm_core(const uint16_t* __restrict__ A,
                                          const uint16_t* __restrict__ W,
                                          const uint16_t* __restrict__ bias,
                                          void* __restrict__ C,
                                          int mode, int f32out)
{
    constexpr int N = DM, K = DM;
    __shared__ __align__(16) uint16_t sA[128][40];   // stride 80 B
    __shared__ __align__(16) uint16_t sB[128][40];

    const int tid  = threadIdx.x;
    const int lane = tid & 63;
    const int wid  = tid >> 6;
    const int ln15 = lane & 15;
    const int quad = lane >> 4;
    const int m0 = blockIdx.y * 128;
    const int n0 = blockIdx.x * 128;
    const int wm = (wid & 1) * 64;
    const int wn = (wid >> 1) * 64;

    v4f acc[4][4];
    const v4f vzero = {0.f, 0.f, 0.f, 0.f};
#pragma unroll
    for (int i = 0; i < 4; i++)
#pragma unroll
        for (int j = 0; j < 4; j++) acc[i][j] = vzero;

    const int r0 = tid >> 2;
    const int c0 = (tid & 3) * 8;

    for (int k0 = 0; k0 < K; k0 += 32) {
        uint4 a0 = *(const uint4*)&A[(size_t)(m0 + r0)      * K + k0 + c0];
        uint4 a1 = *(const uint4*)&A[(size_t)(m0 + r0 + 64) * K + k0 + c0];
        uint4 b0 = *(const uint4*)&W[(size_t)(n0 + r0)      * K + k0 + c0];
        uint4 b1 = *(const uint4*)&W[(size_t)(n0 + r0 + 64) * K + k0 + c0];
        *(uint4*)&sA[r0][c0]      = a0;
        *(uint4*)&sA[r0 + 64][c0] = a1;
        *(uint4*)&sB[r0][c0]      = b0;
        *(uint4*)&sB[r0 + 64][c0] = b1;
        __syncthreads();

        v8bf af[4], bfv[4];
#pragma unroll
        for (int i = 0; i < 4; i++)
            af[i] = *(const v8bf*)&sA[wm + i * 16 + ln15][quad * 8];
#pragma unroll
        for (int j = 0; j < 4; j++)
            bfv[j] = *(const v8bf*)&sB[wn + j * 16 + ln15][quad * 8];
#pragma unroll
        for (int i = 0; i < 4; i++)
#pragma unroll
            for (int j = 0; j < 4; j++)
                acc[i][j] = __builtin_amdgcn_mfma_f32_16x16x32_bf16(
                    af[i], bfv[j], acc[i][j], 0, 0, 0);
        __syncthreads();
    }

    // C/D layout: col=lane&15, row=quad*4+reg  [verified m89/m91]
#pragma unroll
    for (int i = 0; i < 4; i++) {
#pragma unroll
        for (int j = 0; j < 4; j++) {
#pragma unroll
            for (int r = 0; r < 4; r++) {
                int m = m0 + wm + i * 16 + quad * 4 + r;
                int n = n0 + wn + j * 16 + ln15;
                float val = acc[i][j][r] + bf2f(bias[n]);
                if (mode == 3) {
                    size_t idx = (size_t)m * N + n;
                    if (f32out) ((float*)C)[idx] = val;
                    else        ((uint16_t*)C)[idx] = f2bf(val);
                } else {
                    int b = m >> 11, s = m & (SEQ - 1);
                    int h = n >> 6,  d = n & (DK - 1);
                    size_t idx;
                    if (mode == 2)
                        idx = (((size_t)(b * NH + h) * DK + d) * SEQ) + s;
                    else
                        idx = (((size_t)(b * NH + h) * SEQ + s) * DK) + d;
                    ((uint16_t*)C)[idx] = f2bf(val);
                }
            }
        }
    }
}

__global__ __launch_bounds__(256) void qkv_proj_kernel(
    const uint16_t* __restrict__ q,  const uint16_t* __restrict__ k,
    const uint16_t* __restrict__ v,
    const uint16_t* __restrict__ wq, const uint16_t* __restrict__ bq,
    const uint16_t* __restrict__ wk, const uint16_t* __restrict__ bk,
    const uint16_t* __restrict__ wv, const uint16_t* __restrict__ bv,
    uint16_t* __restrict__ qo, uint16_t* __restrict__ ko,
    uint16_t* __restrict__ vto)
{
    int z = blockIdx.z;
    const uint16_t* A  = (z == 0) ? q  : (z == 1) ? k  : v;
    const uint16_t* W  = (z == 0) ? wq : (z == 1) ? wk : wv;
    const uint16_t* Bi = (z == 0) ? bq : (z == 1) ? bk : bv;
    uint16_t*       O  = (z == 0) ? qo : (z == 1) ? ko : vto;
    gemm_core(A, W, Bi, O, (z == 2) ? 2 : 0, 0);
}

__global__ __launch_bounds__(256) void out_proj_kernel(
    const uint16_t* __restrict__ A, const uint16_t* __restrict__ W,
    const uint16_t* __restrict__ Bi, void* __restrict__ O,
    const uint32_t* __restrict__ flag)
{
    gemm_core(A, W, Bi, O, 3, (int)(*flag));
}

// ---------------------------------------------------------------------------
// Flash-style causal attention. Grid (S/128, H, B), 4 waves, wave w owns
// q rows [w*32, w*32+32). Separate sK (no aliasing); sP is wave-private
// (each wave writes+reads only its own 32-row band) -> 2 barriers/K-tile.
// ---------------------------------------------------------------------------
__global__ __launch_bounds__(256) void attn_kernel(
    const uint16_t* __restrict__ Qw, const uint16_t* __restrict__ Kw,
    const uint16_t* __restrict__ VTw, uint16_t* __restrict__ Ow)
{
    __shared__ __align__(16) uint16_t sK[128][80];    // 20480 B, stride 160 B
    __shared__ __align__(16) uint16_t sP[128][136];   // 34816 B
    __shared__ __align__(16) uint16_t sVT[64][136];   // 17408 B

    const int tid  = threadIdx.x;
    const int lane = tid & 63;
    const int wid  = tid >> 6;
    const int ln15 = lane & 15;
    const int quad = lane >> 4;
    const int qi = blockIdx.x, h = blockIdx.y, b = blockIdx.z;
    const float NEG = -30000.0f;

    const uint16_t* Qb  = Qw  + (size_t)(b * NH + h) * SEQ * DK;
    const uint16_t* Kb  = Kw  + (size_t)(b * NH + h) * SEQ * DK;
    const uint16_t* VTb = VTw + (size_t)(b * NH + h) * DK * SEQ;

    // Q fragments: A[m=lane&15][k=quad*8+j]
    v8bf qa[2][2];
#pragma unroll
    for (int tm = 0; tm < 2; tm++)
#pragma unroll
        for (int ks = 0; ks < 2; ks++)
            qa[tm][ks] = *(const v8bf*)&Qb[(size_t)(qi * 128 + wid * 32 + tm * 16 + ln15) * DK
                                           + ks * 32 + quad * 8];

    const v4f vzero = {0.f, 0.f, 0.f, 0.f};
    v4f o_acc[2][4];
#pragma unroll
    for (int tm = 0; tm < 2; tm++)
#pragma unroll
        for (int tn = 0; tn < 4; tn++) o_acc[tm][tn] = vzero;
    float mrow[2][4], lrow[2][4];
#pragma unroll
    for (int tm = 0; tm < 2; tm++)
#pragma unroll
        for (int r = 0; r < 4; r++) { mrow[tm][r] = NEG; lrow[tm][r] = 0.f; }

    for (int j = 0; j <= qi; j++) {
        __syncthreads();   // prior QK^T sK reads + PV sVT reads done

        const uint16_t* Ksrc = Kb + (size_t)j * 128 * DK;
#pragma unroll
        for (int t = 0; t < 4; t++) {
            int s = tid + t * 256;
            int row = s >> 3, cs = (s & 7) * 8;
            *(uint4*)&sK[row][cs] = *(const uint4*)&Ksrc[(size_t)row * DK + cs];
        }
#pragma unroll
        for (int t = 0; t < 4; t++) {
            int s = tid + t * 256;
            int row = s >> 4, cs = (s & 15) * 8;
            *(uint4*)&sVT[row][cs] =
                *(const uint4*)&VTb[(size_t)row * SEQ + j * 128 + cs];
        }
        __syncthreads();

        // S = Q @ K^T, 32 rows x 128 cols per wave
        v4f sacc[2][8];
#pragma unroll
        for (int tm = 0; tm < 2; tm++)
#pragma unroll
            for (int tn = 0; tn < 8; tn++) sacc[tm][tn] = vzero;
#pragma unroll
        for (int tn = 0; tn < 8; tn++) {
            v8bf k0 = *(const v8bf*)&sK[tn * 16 + ln15][quad * 8];
            v8bf k1 = *(const v8bf*)&sK[tn * 16 + ln15][32 + quad * 8];
#pragma unroll
            for (int tm = 0; tm < 2; tm++) {
                sacc[tm][tn] = __builtin_amdgcn_mfma_f32_16x16x32_bf16(
                    qa[tm][0], k0, sacc[tm][tn], 0, 0, 0);
                sacc[tm][tn] = __builtin_amdgcn_mfma_f32_16x16x32_bf16(
                    qa[tm][1], k1, sacc[tm][tn], 0, 0, 0);
            }
        }

        const bool diag = (j == qi);
        // online softmax; row stats private to each 16-lane group
#pragma unroll
        for (int tm = 0; tm < 2; tm++) {
#pragma unroll
            for (int r = 0; r < 4; r++) {
                int row_l = wid * 32 + tm * 16 + quad * 4 + r;
                int grow  = qi * 128 + row_l;
                float sv[8];
                float mx = NEG;
#pragma unroll
                for (int tn = 0; tn < 8; tn++) {
                    float x = sacc[tm][tn][r] * 0.125f;  // 1/sqrt(64)
                    if (diag) {
                        int col = j * 128 + tn * 16 + ln15;
                        if (col > grow) x = NEG;
                    }
                    sv[tn] = x;
                    mx = fmaxf(mx, x);
                }
#pragma unroll
                for (int off = 1; off < 16; off <<= 1)
                    mx = fmaxf(mx, __shfl_xor(mx, off, 64));
                float mnew  = fmaxf(mrow[tm][r], mx);
                float alpha = __expf(mrow[tm][r] - mnew);
                float rs = 0.f;
#pragma unroll
                for (int tn = 0; tn < 8; tn++) {
                    float p = __expf(sv[tn] - mnew);
                    rs += p;
                    sP[row_l][tn * 16 + ln15] = f2bf(p);
                }
#pragma unroll
                for (int off = 1; off < 16; off <<= 1)
                    rs += __shfl_xor(rs, off, 64);
                lrow[tm][r] = lrow[tm][r] * alpha + rs;
                mrow[tm][r] = mnew;
#pragma unroll
                for (int tn4 = 0; tn4 < 4; tn4++)
                    o_acc[tm][tn4][r] *= alpha;
            }
        }
        // no barrier: each wave reads only its own sP band below

        // O += P @ V
#pragma unroll
        for (int ks = 0; ks < 4; ks++) {
            v8bf pf0 = *(const v8bf*)&sP[wid * 32 + ln15][ks * 32 + quad * 8];
            v8bf pf1 = *(const v8bf*)&sP[wid * 32 + 16 + ln15][ks * 32 + quad * 8];
#pragma unroll
            for (int tn4 = 0; tn4 < 4; tn4++) {
                v8bf vf = *(const v8bf*)&sVT[tn4 * 16 + ln15][ks * 32 + quad * 8];
                o_acc[0][tn4] = __builtin_amdgcn_mfma_f32_16x16x32_bf16(
                    pf0, vf, o_acc[0][tn4], 0, 0, 0);
                o_acc[1][tn4] = __builtin_amdgcn_mfma_f32_16x16x32_bf16(
                    pf1, vf, o_acc[1][tn4], 0, 0, 0);
            }
        }
    }

#pragma unroll
    for (int tm = 0; tm < 2; tm++) {
#pragma unroll
        for (int r = 0; r < 4; r++) {
            float inv = 1.f / fmaxf(lrow[tm][r], 1e-20f);
            int grow = qi * 128 + wid * 32 + tm * 16 + quad * 4 + r;
#pragma unroll
            for (int tn4 = 0; tn4 < 4; tn4++) {
                int d = tn4 * 16 + ln15;
                float val = o_acc[tm][tn4][r] * inv;
                Ow[((size_t)b * SEQ + grow) * DM + h * DK + d] = f2bf(val);
            }
        }
    }
}

extern "C" void kernel_launch(void* const* d_in, const int* in_sizes, int n_in,
                              void* d_out, int out_size, void* d_ws, size_t ws_size,
                              hipStream_t stream)
{
    (void)in_sizes; (void)n_in; (void)out_size; (void)ws_size;
    uint16_t* ws = (uint16_t*)d_ws;
    uint32_t* flag = (uint32_t*)(ws + FLAG_OFF);

    uint16_t* q_ws  = ws;
    uint16_t* k_ws  = ws + MEG4;
    uint16_t* vt_ws = ws + 2 * MEG4;
    uint16_t* o_ws  = ws + 3 * MEG4;
    uint16_t* qs  = ws + STAGE_BASE;
    uint16_t* ks  = ws + STAGE_BASE + MEG4;
    uint16_t* vs  = ws + STAGE_BASE + 2 * MEG4;
    uint16_t* wqs = ws + 7 * MEG4;
    uint16_t* wks = ws + 7 * MEG4 + MEG1;
    uint16_t* wvs = ws + 7 * MEG4 + 2 * MEG1;
    uint16_t* wos = ws + 7 * MEG4 + 3 * MEG1;
    uint16_t* bqs = ws + SB;
    uint16_t* bks = ws + SB + 1024;
    uint16_t* bvs = ws + SB + 2048;
    uint16_t* bos = ws + SB + 3072;

    detect_kernel<<<1, 1024, 0, stream>>>((const uint16_t*)d_in[0], flag);
    convert_kernel<<<dim3(2048, 11), 256, 0, stream>>>(
        d_in[0], d_in[1], d_in[2], d_in[4], d_in[5], d_in[6], d_in[7],
        d_in[8], d_in[9], d_in[10], d_in[11], ws, flag);

    dim3 blk(256);
    qkv_proj_kernel<<<dim3(8, 32, 3), blk, 0, stream>>>(
        qs, ks, vs, wqs, bqs, wks, bks, wvs, bvs, q_ws, k_ws, vt_ws);
    attn_kernel<<<dim3(SEQ / 128, NH, BATCH), blk, 0, stream>>>(
        q_ws, k_ws, vt_ws, o_ws);
    out_proj_kernel<<<dim3(8, 32, 1), blk, 0, stream>>>(o_ws, wos, bos, d_out, flag);
}

// Round 4
// 287.364 us; speedup vs baseline: 1.4236x; 1.4236x over previous
//
#include <hip/hip_runtime.h>
#include <stdint.h>

#define BATCH 2
#define SEQ   2048
#define DM    1024
#define NH    16
#define DK    64

#define MEG4 4194304UL
#define MEG1 1048576UL
// ws layout (bf16 element offsets):
//   [0, 4M)    q_ws   (Q proj, [B,H,S,dk])
//   [4M, 8M)   k_ws   (K proj, [B,H,S,dk])
//   [8M, 12M)  vt_ws  (V proj transposed, [B,H,dk,S])
//   [12M,16M)  o_ws   (attn out, [B,S,D])
//   [16M,20M)  staged q ; [20M,24M) k ; [24M,28M) v
//   [28M,29M)  wq ; [29M,30M) wk ; [30M,31M) wv ; [31M,32M) wo
//   [32M + 1024*{0,1,2,3})  bq,bk,bv,bo
#define STAGE_BASE (4 * MEG4)
#define SB         (8 * MEG4)

typedef __bf16 v8bf __attribute__((ext_vector_type(8)));
typedef float  v4f  __attribute__((ext_vector_type(4)));

static __device__ __forceinline__ float bf2f(uint16_t u) {
    union { uint32_t i; float f; } c; c.i = ((uint32_t)u) << 16; return c.f;
}
static __device__ __forceinline__ uint16_t f2bf(float f) {
    union { float f; uint32_t i; } c; c.f = f;
    uint32_t x = c.i;
    return (uint16_t)((x + 0x7fffu + ((x >> 16) & 1u)) >> 16);
}

// ---------------------------------------------------------------------------
// Inputs are fp32 (confirmed R3: bf16 interpretation NaNs, fp32 passes).
// Stage all 11 tensors into ws as bf16.
// ---------------------------------------------------------------------------
__global__ __launch_bounds__(256) void convert_kernel(
    const float* s0, const float* s1, const float* s2, const float* s3,
    const float* s4, const float* s5, const float* s6, const float* s7,
    const float* s8, const float* s9, const float* s10,
    uint16_t* __restrict__ ws)
{
    // z order: q,k,v, wq,bq, wk,bk, wv,bv, wo,bo
    constexpr size_t SZ[11]  = {MEG4, MEG4, MEG4, MEG1, 1024, MEG1, 1024,
                                MEG1, 1024, MEG1, 1024};
    constexpr size_t OFF[11] = {STAGE_BASE, STAGE_BASE + MEG4, STAGE_BASE + 2 * MEG4,
                                7 * MEG4,          SB + 0,
                                7 * MEG4 + MEG1,   SB + 1024,
                                7 * MEG4 + 2*MEG1, SB + 2048,
                                7 * MEG4 + 3*MEG1, SB + 3072};
    const int z = blockIdx.y;
    size_t i0 = ((size_t)blockIdx.x * 256 + threadIdx.x) * 8;
    if (i0 >= SZ[z]) return;
    const float* src;
    switch (z) {
        case 0: src = s0; break;  case 1: src = s1; break;
        case 2: src = s2; break;  case 3: src = s3; break;
        case 4: src = s4; break;  case 5: src = s5; break;
        case 6: src = s6; break;  case 7: src = s7; break;
        case 8: src = s8; break;  case 9: src = s9; break;
        default: src = s10; break;
    }
    const float* s = src + i0;
    uint16_t* dst = ws + OFF[z] + i0;
#pragma unroll
    for (int t = 0; t < 8; t++) dst[t] = f2bf(s[t]);
}

// ---------------------------------------------------------------------------
// gemm_bt core: C[M,N] = A[M,K] @ W[N,K]^T + bias[N], M=4096, N=K=1024.
// 128x128 block tile, BK=32, 4 waves 2x2, 16x16x32 bf16 MFMA.
// mode: 0 -> [B,H,S,dk]; 2 -> [B,H,dk,S]; 3 -> row-major [M,N] fp32 out.
// ---------------------------------------------------------------------------
__device__ __forceinline__ void gemm_core(const uint16_t* __restrict__ A,
                                          const uint16_t* __restrict__ W,
                                          const uint16_t* __restrict__ bias,
                                          void* __restrict__ C,
                                          int mode)
{
    constexpr int N = DM, K = DM;
    __shared__ __align__(16) uint16_t sA[128][40];   // stride 80 B
    __shared__ __align__(16) uint16_t sB[128][40];

    const int tid  = threadIdx.x;
    const int lane = tid & 63;
    const int wid  = tid >> 6;
    const int ln15 = lane & 15;
    const int quad = lane >> 4;
    const int m0 = blockIdx.y * 128;
    const int n0 = blockIdx.x * 128;
    const int wm = (wid & 1) * 64;
    const int wn = (wid >> 1) * 64;

    v4f acc[4][4];
    const v4f vzero = {0.f, 0.f, 0.f, 0.f};
#pragma unroll
    for (int i = 0; i < 4; i++)
#pragma unroll
        for (int j = 0; j < 4; j++) acc[i][j] = vzero;

    const int r0 = tid >> 2;
    const int c0 = (tid & 3) * 8;

    for (int k0 = 0; k0 < K; k0 += 32) {
        uint4 a0 = *(const uint4*)&A[(size_t)(m0 + r0)      * K + k0 + c0];
        uint4 a1 = *(const uint4*)&A[(size_t)(m0 + r0 + 64) * K + k0 + c0];
        uint4 b0 = *(const uint4*)&W[(size_t)(n0 + r0)      * K + k0 + c0];
        uint4 b1 = *(const uint4*)&W[(size_t)(n0 + r0 + 64) * K + k0 + c0];
        *(uint4*)&sA[r0][c0]      = a0;
        *(uint4*)&sA[r0 + 64][c0] = a1;
        *(uint4*)&sB[r0][c0]      = b0;
        *(uint4*)&sB[r0 + 64][c0] = b1;
        __syncthreads();

        v8bf af[4], bfv[4];
#pragma unroll
        for (int i = 0; i < 4; i++)
            af[i] = *(const v8bf*)&sA[wm + i * 16 + ln15][quad * 8];
#pragma unroll
        for (int j = 0; j < 4; j++)
            bfv[j] = *(const v8bf*)&sB[wn + j * 16 + ln15][quad * 8];
#pragma unroll
        for (int i = 0; i < 4; i++)
#pragma unroll
            for (int j = 0; j < 4; j++)
                acc[i][j] = __builtin_amdgcn_mfma_f32_16x16x32_bf16(
                    af[i], bfv[j], acc[i][j], 0, 0, 0);
        __syncthreads();
    }

    // C/D layout: col=lane&15, row=quad*4+reg  [verified m89/m91]
#pragma unroll
    for (int i = 0; i < 4; i++) {
#pragma unroll
        for (int j = 0; j < 4; j++) {
#pragma unroll
            for (int r = 0; r < 4; r++) {
                int m = m0 + wm + i * 16 + quad * 4 + r;
                int n = n0 + wn + j * 16 + ln15;
                float val = acc[i][j][r] + bf2f(bias[n]);
                if (mode == 3) {
                    ((float*)C)[(size_t)m * N + n] = val;
                } else {
                    int b = m >> 11, s = m & (SEQ - 1);
                    int h = n >> 6,  d = n & (DK - 1);
                    size_t idx;
                    if (mode == 2)
                        idx = (((size_t)(b * NH + h) * DK + d) * SEQ) + s;
                    else
                        idx = (((size_t)(b * NH + h) * SEQ + s) * DK) + d;
                    ((uint16_t*)C)[idx] = f2bf(val);
                }
            }
        }
    }
}

__global__ __launch_bounds__(256) void qkv_proj_kernel(
    const uint16_t* __restrict__ q,  const uint16_t* __restrict__ k,
    const uint16_t* __restrict__ v,
    const uint16_t* __restrict__ wq, const uint16_t* __restrict__ bq,
    const uint16_t* __restrict__ wk, const uint16_t* __restrict__ bk,
    const uint16_t* __restrict__ wv, const uint16_t* __restrict__ bv,
    uint16_t* __restrict__ qo, uint16_t* __restrict__ ko,
    uint16_t* __restrict__ vto)
{
    int z = blockIdx.z;
    const uint16_t* A  = (z == 0) ? q  : (z == 1) ? k  : v;
    const uint16_t* W  = (z == 0) ? wq : (z == 1) ? wk : wv;
    const uint16_t* Bi = (z == 0) ? bq : (z == 1) ? bk : bv;
    uint16_t*       O  = (z == 0) ? qo : (z == 1) ? ko : vto;
    gemm_core(A, W, Bi, O, (z == 2) ? 2 : 0);
}

__global__ __launch_bounds__(256) void out_proj_kernel(
    const uint16_t* __restrict__ A, const uint16_t* __restrict__ W,
    const uint16_t* __restrict__ Bi, float* __restrict__ O)
{
    gemm_core(A, W, Bi, O, 3);
}

// ---------------------------------------------------------------------------
// Flash-style causal attention, work-balanced.
// 64-row Q tiles (32 of them per b,h). Block p handles the PAIR (p, 31-p):
// per-block K-tile count = (p>>1) + ((31-p)>>1) + 2 = 17 for every p ->
// uniform MFMA work. Both Q-tiles share each staged K/V tile.
// Grid (16, H, B) = 512 blocks, 256 thr (4 waves); wave w owns rows
// [16w,16w+16) of each tile. sP bands are wave-private (no extra barrier).
// ---------------------------------------------------------------------------
__global__ __launch_bounds__(256) void attn_kernel(
    const uint16_t* __restrict__ Qw, const uint16_t* __restrict__ Kw,
    const uint16_t* __restrict__ VTw, uint16_t* __restrict__ Ow)
{
    __shared__ __align__(16) uint16_t sK[128][72];    // 18432 B (144B stride)
    __shared__ __align__(16) uint16_t sVT[64][136];   // 17408 B
    __shared__ __align__(16) uint16_t sP[128][136];   // 34816 B (rows: tile*64+..)

    const int tid  = threadIdx.x;
    const int lane = tid & 63;
    const int wid  = tid >> 6;
    const int ln15 = lane & 15;
    const int quad = lane >> 4;
    const int p = blockIdx.x, h = blockIdx.y, b = blockIdx.z;
    const float NEG = -30000.0f;

    const int qt[2]   = { p, 31 - p };          // 64-row tile indices
    const int jmax[2] = { p >> 1, (31 - p) >> 1 };

    const uint16_t* Qb  = Qw  + (size_t)(b * NH + h) * SEQ * DK;
    const uint16_t* Kb  = Kw  + (size_t)(b * NH + h) * SEQ * DK;
    const uint16_t* VTb = VTw + (size_t)(b * NH + h) * DK * SEQ;

    // Q fragments: A[m=lane&15][k=quad*8+j]; wave w -> rows [16w,16w+16)
    v8bf qa[2][2];
#pragma unroll
    for (int t = 0; t < 2; t++)
#pragma unroll
        for (int ks = 0; ks < 2; ks++)
            qa[t][ks] = *(const v8bf*)&Qb[(size_t)(qt[t] * 64 + wid * 16 + ln15) * DK
                                          + ks * 32 + quad * 8];

    const v4f vzero = {0.f, 0.f, 0.f, 0.f};
    v4f o_acc[2][4];
#pragma unroll
    for (int t = 0; t < 2; t++)
#pragma unroll
        for (int tn = 0; tn < 4; tn++) o_acc[t][tn] = vzero;
    float mrow[2][4], lrow[2][4];
#pragma unroll
    for (int t = 0; t < 2; t++)
#pragma unroll
        for (int r = 0; r < 4; r++) { mrow[t][r] = NEG; lrow[t][r] = 0.f; }

    for (int j = 0; j <= jmax[1]; j++) {
        __syncthreads();   // prior QK^T sK reads + PV sVT reads done

        const uint16_t* Ksrc = Kb + (size_t)j * 128 * DK;
#pragma unroll
        for (int t4 = 0; t4 < 4; t4++) {
            int s = tid + t4 * 256;
            int row = s >> 3, cs = (s & 7) * 8;
            *(uint4*)&sK[row][cs] = *(const uint4*)&Ksrc[(size_t)row * DK + cs];
        }
#pragma unroll
        for (int t4 = 0; t4 < 4; t4++) {
            int s = tid + t4 * 256;
            int row = s >> 4, cs = (s & 15) * 8;
            *(uint4*)&sVT[row][cs] =
                *(const uint4*)&VTb[(size_t)row * SEQ + j * 128 + cs];
        }
        __syncthreads();

#pragma unroll
        for (int t = 0; t < 2; t++) {
            if (j > jmax[t]) continue;   // block-uniform branch
            // S = Q_t @ K^T : wave's 16 rows x 128 cols
            v4f sacc[8];
#pragma unroll
            for (int tn = 0; tn < 8; tn++) sacc[tn] = vzero;
#pragma unroll
            for (int tn = 0; tn < 8; tn++) {
                v8bf k0 = *(const v8bf*)&sK[tn * 16 + ln15][quad * 8];
                v8bf k1 = *(const v8bf*)&sK[tn * 16 + ln15][32 + quad * 8];
                sacc[tn] = __builtin_amdgcn_mfma_f32_16x16x32_bf16(
                    qa[t][0], k0, sacc[tn], 0, 0, 0);
                sacc[tn] = __builtin_amdgcn_mfma_f32_16x16x32_bf16(
                    qa[t][1], k1, sacc[tn], 0, 0, 0);
            }
            const bool diag = (j == (qt[t] >> 1));
            // online softmax; row stats private to each 16-lane group
#pragma unroll
            for (int r = 0; r < 4; r++) {
                int rloc = quad * 4 + r;                     // row in 16-band
                int grow = qt[t] * 64 + wid * 16 + rloc;     // global q row
                float sv[8];
                float mx = NEG;
#pragma unroll
                for (int tn = 0; tn < 8; tn++) {
                    float x = sacc[tn][r] * 0.125f;          // 1/sqrt(64)
                    if (diag) {
                        int col = j * 128 + tn * 16 + ln15;
                        if (col > grow) x = NEG;
                    }
                    sv[tn] = x;
                    mx = fmaxf(mx, x);
                }
#pragma unroll
                for (int off = 1; off < 16; off <<= 1)
                    mx = fmaxf(mx, __shfl_xor(mx, off, 64));
                float mnew  = fmaxf(mrow[t][r], mx);
                float alpha = __expf(mrow[t][r] - mnew);
                float rs = 0.f;
#pragma unroll
                for (int tn = 0; tn < 8; tn++) {
                    float pv = __expf(sv[tn] - mnew);
                    rs += pv;
                    sP[t * 64 + wid * 16 + rloc][tn * 16 + ln15] = f2bf(pv);
                }
#pragma unroll
                for (int off = 1; off < 16; off <<= 1)
                    rs += __shfl_xor(rs, off, 64);
                lrow[t][r] = lrow[t][r] * alpha + rs;
                mrow[t][r] = mnew;
#pragma unroll
                for (int tn4 = 0; tn4 < 4; tn4++)
                    o_acc[t][tn4][r] *= alpha;
            }
        }

        // O_t += P_t @ V ; wave reads only its own sP band
#pragma unroll
        for (int t = 0; t < 2; t++) {
            if (j > jmax[t]) continue;
#pragma unroll
            for (int ks = 0; ks < 4; ks++) {
                v8bf pf = *(const v8bf*)&sP[t * 64 + wid * 16 + ln15][ks * 32 + quad * 8];
#pragma unroll
                for (int tn4 = 0; tn4 < 4; tn4++) {
                    v8bf vf = *(const v8bf*)&sVT[tn4 * 16 + ln15][ks * 32 + quad * 8];
                    o_acc[t][tn4] = __builtin_amdgcn_mfma_f32_16x16x32_bf16(
                        pf, vf, o_acc[t][tn4], 0, 0, 0);
                }
            }
        }
    }

#pragma unroll
    for (int t = 0; t < 2; t++) {
#pragma unroll
        for (int r = 0; r < 4; r++) {
            float inv = 1.f / fmaxf(lrow[t][r], 1e-20f);
            int grow = qt[t] * 64 + wid * 16 + quad * 4 + r;
#pragma unroll
            for (int tn4 = 0; tn4 < 4; tn4++) {
                int d = tn4 * 16 + ln15;
                float val = o_acc[t][tn4][r] * inv;
                Ow[((size_t)b * SEQ + grow) * DM + h * DK + d] = f2bf(val);
            }
        }
    }
}

extern "C" void kernel_launch(void* const* d_in, const int* in_sizes, int n_in,
                              void* d_out, int out_size, void* d_ws, size_t ws_size,
                              hipStream_t stream)
{
    (void)in_sizes; (void)n_in; (void)out_size; (void)ws_size;
    uint16_t* ws = (uint16_t*)d_ws;

    uint16_t* q_ws  = ws;
    uint16_t* k_ws  = ws + MEG4;
    uint16_t* vt_ws = ws + 2 * MEG4;
    uint16_t* o_ws  = ws + 3 * MEG4;
    uint16_t* qs  = ws + STAGE_BASE;
    uint16_t* ks  = ws + STAGE_BASE + MEG4;
    uint16_t* vs  = ws + STAGE_BASE + 2 * MEG4;
    uint16_t* wqs = ws + 7 * MEG4;
    uint16_t* wks = ws + 7 * MEG4 + MEG1;
    uint16_t* wvs = ws + 7 * MEG4 + 2 * MEG1;
    uint16_t* wos = ws + 7 * MEG4 + 3 * MEG1;
    uint16_t* bqs = ws + SB;
    uint16_t* bks = ws + SB + 1024;
    uint16_t* bvs = ws + SB + 2048;
    uint16_t* bos = ws + SB + 3072;

    convert_kernel<<<dim3(2048, 11), 256, 0, stream>>>(
        (const float*)d_in[0], (const float*)d_in[1], (const float*)d_in[2],
        (const float*)d_in[4], (const float*)d_in[5], (const float*)d_in[6],
        (const float*)d_in[7], (const float*)d_in[8], (const float*)d_in[9],
        (const float*)d_in[10], (const float*)d_in[11], ws);

    dim3 blk(256);
    qkv_proj_kernel<<<dim3(8, 32, 3), blk, 0, stream>>>(
        qs, ks, vs, wqs, bqs, wks, bks, wvs, bvs, q_ws, k_ws, vt_ws);
    attn_kernel<<<dim3(16, NH, BATCH), blk, 0, stream>>>(
        q_ws, k_ws, vt_ws, o_ws);
    out_proj_kernel<<<dim3(8, 32, 1), blk, 0, stream>>>(o_ws, wos, bos, (float*)d_out);
}